// Round 13
// baseline (2190.486 us; speedup 1.0000x reference)
//
#include <hip/hip_runtime.h>

#define B_   8
#define N_   8192
#define CIN  64
#define COUT 128
#define M_   2048
#define K_   16

#define MAGIC 0x5AFEC0DEu

typedef float v2f __attribute__((ext_vector_type(2)));

// ---------------------------------------------------------------------------
// DPP wave-64 reduce helpers (VALU-only, no LDS latency).
// ---------------------------------------------------------------------------
template <int CTRL>
__device__ __forceinline__ unsigned long long dpp64(unsigned long long x) {
  int lo = (int)(unsigned)(x & 0xFFFFFFFFull);
  int hi = (int)(unsigned)(x >> 32);
  int dlo = __builtin_amdgcn_update_dpp(lo, lo, CTRL, 0xF, 0xF, false);
  int dhi = __builtin_amdgcn_update_dpp(hi, hi, CTRL, 0xF, 0xF, false);
  return ((unsigned long long)(unsigned)dhi << 32) | (unsigned)dlo;
}

__device__ __forceinline__ unsigned long long readlane_u64(unsigned long long k, int l) {
  unsigned lo = (unsigned)__builtin_amdgcn_readlane((int)(unsigned)(k & 0xFFFFFFFFull), l);
  unsigned hi = (unsigned)__builtin_amdgcn_readlane((int)(unsigned)(k >> 32), l);
  return ((unsigned long long)hi << 32) | lo;
}

__device__ __forceinline__ unsigned long long wave_max_u64(unsigned long long k) {
  unsigned long long t;
  t = dpp64<0x111>(k); k = t > k ? t : k;
  t = dpp64<0x112>(k); k = t > k ? t : k;
  t = dpp64<0x114>(k); k = t > k ? t : k;
  t = dpp64<0x118>(k); k = t > k ? t : k;
  t = dpp64<0x142>(k); k = t > k ? t : k;
  t = dpp64<0x143>(k); k = t > k ? t : k;
  return readlane_u64(k, 63);
}

__device__ __forceinline__ unsigned long long wave_min_u64(unsigned long long k) {
  unsigned long long t;
  t = dpp64<0x111>(k); k = t < k ? t : k;
  t = dpp64<0x112>(k); k = t < k ? t : k;
  t = dpp64<0x114>(k); k = t < k ? t : k;
  t = dpp64<0x118>(k); k = t < k ? t : k;
  t = dpp64<0x142>(k); k = t < k ? t : k;
  t = dpp64<0x143>(k); k = t < k ? t : k;
  return readlane_u64(k, 63);
}

// ---------------------------------------------------------------------------
// 1+2) Merged FPS + MLP. Blocks 0..7 = FPS (one per batch); blocks 8..2055 =
//      MLP tiles. FPS numerics: f32, d = fma(dz,dz,fma(dy,dy,dx*dx)) — R4
//      PROVED this fma form produces the identical selection chain (R2 vs R4
//      differed only here; outputs bit-identical). fminf, u64
//      (d<<32)|(N-1-n) argmax = (max d, min n). Branchless select argmax.
//      publish!=0: p_out streamed in 8 chunks of 256 rows; chunk-c flag
//      released at iter (c+1)*256+1 (after that iteration's barrier => all
//      row stores vmcnt-drained). MLP blocks release mlpDone[bid] after
//      __syncthreads() (drains h stores).
// ---------------------------------------------------------------------------
#define FTH 512
#define FPT 16
#define MROWS2 32

__global__ __launch_bounds__(512) void fps_mlp_kernel(
    const float* __restrict__ p, float* __restrict__ p_out,
    const float* __restrict__ x, const float* __restrict__ W,
    const float* __restrict__ gamma, const float* __restrict__ beta,
    const float* __restrict__ rmean, const float* __restrict__ rvar,
    float* __restrict__ h, unsigned* __restrict__ fpsFlags,
    unsigned* __restrict__ mlpDone, int publish) {
#pragma clang fp contract(off)
  __shared__ __align__(16) unsigned char smem[139776];

  const int tid = threadIdx.x;

  if (blockIdx.x >= 8) {
    // ---------------- MLP tile ----------------
    float* wt = (float*)smem;                   // W^T padded: wt[c*132+o]
    float* xs = (float*)(smem + 33792);         // xs[r*64+c], 32 rows

    const int o  = tid & 127;
    const int rg = tid >> 7;
    const int bid = blockIdx.x - 8;
    const int rowBase = bid * MROWS2;

    for (int idx = tid; idx < COUT * CIN; idx += 512) {
      const int oo = idx >> 6, cc = idx & 63;
      wt[cc * 132 + oo] = W[idx];
    }
    ((float4*)xs)[tid] = ((const float4*)(x + (size_t)rowBase * CIN))[tid];
    __syncthreads();

    float acc[8] = {0.f, 0.f, 0.f, 0.f, 0.f, 0.f, 0.f, 0.f};
#pragma unroll
    for (int c4 = 0; c4 < CIN / 4; c4++) {
      const float w0 = wt[(4 * c4 + 0) * 132 + o];
      const float w1 = wt[(4 * c4 + 1) * 132 + o];
      const float w2 = wt[(4 * c4 + 2) * 132 + o];
      const float w3 = wt[(4 * c4 + 3) * 132 + o];
#pragma unroll
      for (int i = 0; i < 8; i++) {
        const float4 xv = *(const float4*)&xs[(rg * 8 + i) * CIN + c4 * 4];
        acc[i] += xv.x * w0 + xv.y * w1 + xv.z * w2 + xv.w * w3;
      }
    }
    const float mu = rmean[o];
    const float sc = rsqrtf(rvar[o] + 1e-5f) * gamma[o];
    const float bt = beta[o];
#pragma unroll
    for (int i = 0; i < 8; i++) {
      const float v = (acc[i] - mu) * sc + bt;
      h[(size_t)(rowBase + rg * 8 + i) * COUT + o] = fmaxf(v, 0.f);
    }
    __syncthreads();                            // drains all waves' vmcnt
    if (publish && tid == 0)
      __hip_atomic_store(&mlpDone[bid], MAGIC, __ATOMIC_RELEASE,
                         __HIP_MEMORY_SCOPE_AGENT);
    return;
  }

  // ---------------- FPS ----------------
  float4* pc4 = (float4*)smem;                               // 128 KB
  unsigned long long (*wred)[8] =
      (unsigned long long (*)[8])(smem + 131072);
  int* idxHist = (int*)(smem + 131072 + 128);                // 8 KB

  const int b  = blockIdx.x;
  const int wv = tid >> 6;
  const int ln = tid & 63;

  const float* pb = p + (size_t)b * N_ * 3;
  for (int n = tid; n < N_; n += FTH)
    pc4[n] = make_float4(pb[3 * n + 0], pb[3 * n + 1], pb[3 * n + 2], 0.f);
  if (tid == 0) idxHist[0] = 0;
  __syncthreads();

  float4 c0 = pc4[0];
  float cx = c0.x, cy = c0.y, cz = c0.z;
  float* po = p_out + (size_t)b * M_ * 3;

  v2f X2[8], Y2[8], Z2[8], D2[8];
#pragma unroll
  for (int j = 0; j < 8; j++) {
    float4 a = pc4[tid + (2 * j) * FTH];
    float4 c = pc4[tid + (2 * j + 1) * FTH];
    X2[j] = (v2f){a.x, c.x};
    Y2[j] = (v2f){a.y, c.y};
    Z2[j] = (v2f){a.z, c.z};
    D2[j] = (v2f){__builtin_inff(), __builtin_inff()};
  }

  int buf = 0;
  for (int it = 1; it < M_; ++it) {
    const v2f cxv = {cx, cx}, cyv = {cy, cy}, czv = {cz, cz};
    float bd = -1.0f; int bk = 0;
#pragma unroll
    for (int j = 0; j < 8; j++) {
      v2f dx = X2[j] - cxv;
      v2f dy = Y2[j] - cyv;
      v2f dz = Z2[j] - czv;
      v2f d  = __builtin_elementwise_fma(dz, dz,
               __builtin_elementwise_fma(dy, dy, dx * dx));  // R4-proven form
      v2f dm = __builtin_elementwise_min(D2[j], d);
      D2[j] = dm;
      bool gx = dm.x > bd;                       // branchless selects
      bk = gx ? (2 * j) : bk;
      bd = gx ? dm.x : bd;
      bool gy = dm.y > bd;
      bk = gy ? (2 * j + 1) : bk;
      bd = gy ? dm.y : bd;
    }
    const int n = tid + (bk << 9);
    unsigned long long key =
        ((unsigned long long)__float_as_uint(bd) << 32) |
        (unsigned)(N_ - 1 - n);                 // max key => max d, min n
    key = wave_max_u64(key);
    if (ln == 0) wred[buf][wv] = key;
    __syncthreads();                            // the ONLY barrier per iter

    if (publish) {
      if ((it & 255) == 0 && tid < 256) {       // rows of chunk (it>>8)-1
        const int row = ((it >> 8) - 1 << 8) + tid;
        float4 v = pc4[idxHist[row]];
        float* pr = po + (size_t)row * 3;
        pr[0] = v.x; pr[1] = v.y; pr[2] = v.z;
      }
      if ((it & 255) == 1 && it > 256 && tid == 0) {
        const int c = ((it - 1) >> 8) - 1;      // stores drained by barrier
        __hip_atomic_store(&fpsFlags[b * 8 + c], MAGIC, __ATOMIC_RELEASE,
                           __HIP_MEMORY_SCOPE_AGENT);
      }
    }

    unsigned long long kk = wred[buf][ln & 7];
    unsigned long long t;
    t = dpp64<0x111>(kk); kk = t > kk ? t : kk;
    t = dpp64<0x112>(kk); kk = t > kk ? t : kk;
    t = dpp64<0x114>(kk); kk = t > kk ? t : kk;
    const unsigned long long m = readlane_u64(kk, 7);
    const int nw = N_ - 1 - (int)(unsigned)(m & 0xFFFFFFFFu);
    float4 cc = pc4[nw];
    cx = cc.x; cy = cc.y; cz = cc.z;
    if (tid == 0) idxHist[it] = nw;
    buf ^= 1;
  }
  __syncthreads();

  if (publish) {
    if (tid < 256) {                            // chunk 7 rows 1792..2047
      const int row = 1792 + tid;
      float4 v = pc4[idxHist[row]];
      float* pr = po + (size_t)row * 3;
      pr[0] = v.x; pr[1] = v.y; pr[2] = v.z;
    }
    __syncthreads();                            // drain chunk-7 stores
    if (tid == 0)
      __hip_atomic_store(&fpsFlags[b * 8 + 7], MAGIC, __ATOMIC_RELEASE,
                         __HIP_MEMORY_SCOPE_AGENT);
  } else {
    for (int mi = tid; mi < M_; mi += FTH) {
      float4 v = pc4[idxHist[mi]];
      po[mi * 3 + 0] = v.x;
      po[mi * 3 + 1] = v.y;
      po[mi * 3 + 2] = v.z;
    }
  }
}

// ---------------------------------------------------------------------------
// 3) KNN — R10-12 internals verbatim (d2 bits + selection semantics locked).
//    wait!=0: stage pc4 first (overlap), then bounded-spin on this block's
//    fps chunk flag (acquire, agent scope); before gather, bounded-spin on
//    the 256 mlpDone flags of this batch.
// ---------------------------------------------------------------------------
#define UMAXK 0xFFFFFFFFFFFFFFFFull
#define QPB  16

__global__ __launch_bounds__(1024) void knn_kernel(
    const float* __restrict__ p, const float* __restrict__ p_out,
    const float* __restrict__ h, float* __restrict__ y,
    const unsigned* __restrict__ fpsFlags,
    const unsigned* __restrict__ mlpDone, int wait) {
#pragma clang fp contract(off)
  __shared__ float4 pc4[N_];            // 128 KB: x,y,z,sn
  __shared__ int winLds[QPB][K_];

  const int t    = threadIdx.x;
  const int wv   = t >> 6;
  const int lane = t & 63;
  const int b    = blockIdx.x & 7;
  const int grp  = blockIdx.x >> 3;     // 0..127
  const int q    = b * M_ + grp * QPB + wv;

  // stage p[b] + sn (independent of p_out -> overlaps the wait)
  const float* pb = p + (size_t)b * N_ * 3;
  for (int n = t; n < N_; n += 1024) {
    float xx = pb[3 * n + 0], yy = pb[3 * n + 1], zz = pb[3 * n + 2];
    float sn = (xx * xx + yy * yy) + zz * zz;   // numpy sum, no fma
    pc4[n] = make_float4(xx, yy, zz, sn);
  }

  if (wait && t == 0) {                 // spin for my chunk's p_out
    const int chunk = grp >> 4;
    int guard = 0;
    while (__hip_atomic_load(&fpsFlags[b * 8 + chunk], __ATOMIC_ACQUIRE,
                             __HIP_MEMORY_SCOPE_AGENT) != MAGIC &&
           ++guard < (1 << 23))
      __builtin_amdgcn_s_sleep(2);
  }
  __syncthreads();                      // staging + flag both satisfied

  const float qx = p_out[q * 3 + 0];
  const float qy = p_out[q * 3 + 1];
  const float qz = p_out[q * 3 + 2];
  const float sq = (qx * qx + qy * qy) + qz * qz;   // numpy sum, no fma

  unsigned long long c0 = UMAXK, c1 = UMAXK, c2 = UMAXK, c3 = UMAXK;
#pragma unroll 4
  for (int j = 0; j < 128; j++) {
    const int n = lane + (j << 6);
    float4 v = pc4[n];
    float dot = __builtin_fmaf(qz, v.z,
                __builtin_fmaf(qy, v.y, qx * v.x)); // BLAS fma chain, k asc
    float d2 = (sq + v.w) - 2.0f * dot;
    unsigned u = __float_as_uint(d2);
    u ^= (unsigned)((int)u >> 31) | 0x80000000u;    // monotone f32->u32
    unsigned long long key = ((unsigned long long)u << 32) | (unsigned)n;
    if (key < c3) {
      unsigned long long x2 = key, mn;
      mn = x2 < c0 ? x2 : c0; x2 = x2 < c0 ? c0 : x2; c0 = mn;
      mn = x2 < c1 ? x2 : c1; x2 = x2 < c1 ? c1 : x2; c1 = mn;
      mn = x2 < c2 ? x2 : c2; x2 = x2 < c2 ? c2 : x2; c2 = mn;
      c3 = x2 < c3 ? x2 : c3;
    }
  }

  int count = 4;
  unsigned long long em0 = 0ull, em1 = 0ull;
  unsigned long long mykey = UMAXK;

  for (int k = 0; k < K_; k++) {
    unsigned long long cnd = (count > 0) ? c0 : UMAXK;
    unsigned long long win = wave_min_u64(cnd);
    if (lane == k) mykey = win;
    const int nstar = (int)(unsigned)(win & 0xFFFFFFFFu);
    if ((nstar & 63) == lane) {
      const int j = nstar >> 6;
      if (j < 64) em0 |= 1ull << j; else em1 |= 1ull << (j - 64);
      c0 = c1; c1 = c2; c2 = c3; c3 = UMAXK; count--;
      if (count == 0 && k < K_ - 1) {
        c0 = c1 = c2 = c3 = UMAXK;
        for (int j2 = 0; j2 < 128; j2++) {
          bool ex = (j2 < 64) ? ((em0 >> j2) & 1ull) : ((em1 >> (j2 - 64)) & 1ull);
          if (!ex) {
            const int n2 = lane + (j2 << 6);
            float4 v = pc4[n2];
            float dot = __builtin_fmaf(qz, v.z,
                        __builtin_fmaf(qy, v.y, qx * v.x));
            float d2 = (sq + v.w) - 2.0f * dot;
            unsigned u = __float_as_uint(d2);
            u ^= (unsigned)((int)u >> 31) | 0x80000000u;
            unsigned long long kk2 = ((unsigned long long)u << 32) | (unsigned)n2;
            if (kk2 < c3) {
              unsigned long long x2 = kk2, mn;
              mn = x2 < c0 ? x2 : c0; x2 = x2 < c0 ? c0 : x2; c0 = mn;
              mn = x2 < c1 ? x2 : c1; x2 = x2 < c1 ? c1 : x2; c1 = mn;
              mn = x2 < c2 ? x2 : c2; x2 = x2 < c2 ? c2 : x2; c2 = mn;
              c3 = x2 < c3 ? x2 : c3;
            }
          }
        }
        count = 4;
      }
    }
  }

  if (lane < K_) winLds[wv][lane] = (int)(unsigned)(mykey & 0xFFFFFFFFu);

  if (wait && t < 256) {                // h readiness: batch b's mlp blocks
    int guard = 0;
    while (__hip_atomic_load(&mlpDone[b * 256 + t], __ATOMIC_ACQUIRE,
                             __HIP_MEMORY_SCOPE_AGENT) != MAGIC &&
           ++guard < (1 << 23))
      __builtin_amdgcn_s_sleep(2);
  }
  __syncthreads();

  const float* hb = h + (size_t)b * N_ * COUT;
  float2 acc = make_float2(-__builtin_inff(), -__builtin_inff());
#pragma unroll
  for (int i = 0; i < K_; i++) {
    const int n = winLds[wv][i];
    float2 v = *(const float2*)(hb + (size_t)n * COUT + lane * 2);
    acc.x = fmaxf(acc.x, v.x);
    acc.y = fmaxf(acc.y, v.y);
  }
  *(float2*)(y + (size_t)q * COUT + lane * 2) = acc;
}

// ---------------------------------------------------------------------------
extern "C" void kernel_launch(void* const* d_in, const int* in_sizes, int n_in,
                              void* d_out, int out_size, void* d_ws, size_t ws_size,
                              hipStream_t stream) {
  const float* x     = (const float*)d_in[0];
  const float* p     = (const float*)d_in[1];
  const float* W     = (const float*)d_in[2];
  const float* gamma = (const float*)d_in[3];
  const float* beta  = (const float*)d_in[4];
  const float* rmean = (const float*)d_in[5];
  const float* rvar  = (const float*)d_in[6];

  float* y     = (float*)d_out;                       // (B, M, COUT)
  float* p_out = y + (size_t)B_ * M_ * COUT;          // (B, M, 3)
  float* h     = (float*)d_ws;                        // (B, N, COUT)

  const size_t hBytes = (size_t)B_ * N_ * COUT * 4;   // 33,554,432
  const int overlap = (ws_size >= hBytes + 16384) ? 1 : 0;  // ws_size is
  unsigned* fpsFlags = (unsigned*)((char*)d_ws + hBytes);   // call-invariant
  unsigned* mlpDone  = fpsFlags + 64;

  fps_mlp_kernel<<<8 + (B_ * N_) / MROWS2, 512, 0, stream>>>(
      p, p_out, x, W, gamma, beta, rmean, rvar, h, fpsFlags, mlpDone, overlap);
  knn_kernel<<<B_ * (M_ / QPB), 1024, 0, stream>>>(
      p, p_out, h, y, fpsFlags, mlpDone, overlap);
}